// Round 18
// baseline (50.045 us; speedup 1.0000x reference)
//
#include <hip/hip_runtime.h>
#include <hip/hip_bf16.h>

#define BATCH 8
#define NTOK 16384

typedef __attribute__((ext_vector_type(8))) short bf16x8;
typedef __attribute__((ext_vector_type(4))) short bf16x4;
typedef __attribute__((ext_vector_type(4))) float f32x4;
typedef __attribute__((ext_vector_type(4))) unsigned int u32x4;

#define MFMA(a, b, c) __builtin_amdgcn_mfma_f32_16x16x32_bf16(a, b, c, 0, 0, 0)

// proven path: RNE f32->bf16 via bit ops
__device__ __forceinline__ short f2bf(float f) {
  unsigned u = __builtin_bit_cast(unsigned, f);
  u = (u + 0x7fffu + ((u >> 16) & 1u)) >> 16;  // RNE
  return (short)u;
}
__device__ __forceinline__ bf16x8 cvt8(f32x4 v0, f32x4 v1) {
  bf16x8 a;
  a[0] = f2bf(v0[0]); a[1] = f2bf(v0[1]); a[2] = f2bf(v0[2]); a[3] = f2bf(v0[3]);
  a[4] = f2bf(v1[0]); a[5] = f2bf(v1[1]); a[6] = f2bf(v1[2]); a[7] = f2bf(v1[3]);
  return a;
}
// HW packed conversion via HIP header (compiler-lowered, NOT hand asm)
__device__ __forceinline__ unsigned pk2(float a, float b) {
  __hip_bfloat162 h = __float22bfloat162_rn(float2{a, b});
  unsigned r;
  __builtin_memcpy(&r, &h, 4);
  return r;
}
__device__ __forceinline__ bf16x8 cvt8pk(f32x4 v0, f32x4 v1) {
  u32x4 w;
  w[0] = pk2(v0[0], v0[1]);
  w[1] = pk2(v0[2], v0[3]);
  w[2] = pk2(v1[0], v1[1]);
  w[3] = pk2(v1[2], v1[3]);
  return __builtin_bit_cast(bf16x8, w);
}

// ---------------- prep: conv weight transpose via padded LDS tile ---------
__global__ __launch_bounds__(256) void prep_k(const float* __restrict__ w_sr,
                                              short* __restrict__ W2T) {
  __shared__ float tile[64 * 65];
  const int o = blockIdx.x;  // 64 blocks
  const float* src = w_sr + (o << 12);
  short* dst = W2T + (o << 12);
  const int tid = threadIdx.x;
#pragma unroll
  for (int k = 0; k < 16; ++k) {
    int idx = k * 256 + tid;
    int c = idx >> 6, t = idx & 63;
    tile[c * 65 + t] = src[idx];
  }
  __syncthreads();
#pragma unroll
  for (int k = 0; k < 16; ++k) {
    int idx = k * 256 + tid;
    int t = idx >> 6, c = idx & 63;
    dst[idx] = f2bf(tile[c * 65 + t]);
  }
}

// ---------------- conv v2: LDS-staged coalesced x, MFMA GEMM, K-split 4 ---
__global__ __launch_bounds__(256, 4) void conv_k(const float* __restrict__ x,
                                                 const short* __restrict__ W2T,
                                                 float* __restrict__ convP) {
  __shared__ short Axl[2 * 128 * 64];  // 32KB: [ti][col][c]
  const int tid = threadIdx.x;
  const int lane = tid & 63;
  const int nt = tid >> 6;
  const int g = lane >> 4;
  const int kq = lane & 15;          // pj
  const int pblk = blockIdx.x >> 2;  // b*16 + pi
  const int split = blockIdx.x & 3;
  const int pbase = pblk << 4;
  const int b = pbase >> 8;
  const int pi = pblk & 15;
  const size_t xb = (size_t)b * NTOK * 64;
  const int y0 = pi * 8 + split * 2;

#pragma unroll
  for (int i = 0; i < 8; ++i) {
    int cid = i * 256 + tid;
    int row = cid >> 3;               // ti*128 + col
    int ti = row >> 7, col = row & 127;
    int slot = (cid & 7) ^ ((col >> 3) & 7);
    const float* src = x + xb + ((size_t)((y0 + ti) * 128 + col) << 6) + ((cid & 7) << 3);
    bf16x8 v = cvt8(*(const f32x4*)src, *(const f32x4*)(src + 4));
    *(bf16x8*)(&Axl[(row << 6) + (slot << 3)]) = v;
  }
  __syncthreads();

  f32x4 acc = (f32x4){0.f, 0.f, 0.f, 0.f};
  const int c0 = split << 5;
#pragma unroll 4
  for (int c32 = c0; c32 < c0 + 32; ++c32) {
    int t = c32 >> 1;
    int ti = (t >> 3) & 1;
    int tj = t & 7;
    int row = ti * 128 + kq * 8 + tj;
    int slot = (((c32 & 1) << 2) + g) ^ (kq & 7);
    bf16x8 a = *(const bf16x8*)(&Axl[(row << 6) + (slot << 3)]);
    bf16x8 wb = *(const bf16x8*)(W2T + ((nt * 16 + kq) << 12) + (c32 << 5) + (g << 3));
    acc = MFMA(a, wb, acc);
  }
#pragma unroll
  for (int r = 0; r < 4; ++r) {
    int prow = pbase + g * 4 + r;
    convP[((split << 11) + prow) * 64 + nt * 16 + kq] = acc[r];
  }
}

// ---------------- fused: bias + LN + kv-proj + folded q/out projections ---
__global__ __launch_bounds__(256) void kvkq_k(
    const float* __restrict__ convP, const float* __restrict__ b_sr,
    const float* __restrict__ ln_g, const float* __restrict__ ln_b,
    const float* __restrict__ w_kv, const float* __restrict__ w_q,
    const float* __restrict__ w_proj, short* __restrict__ KQ,
    short* __restrict__ VPT) {
  __shared__ float wT[64 * 128];   // w_kv [c][d ^ (c&31)]
  __shared__ float wq[64 * 64];    // SCALE*w_q [o][cc]
  __shared__ float wp[64 * 64];    // w_proj [o][d]
  __shared__ float rowz[16][64];
  __shared__ float Kf[16][68];
  __shared__ float Vf[16][68];
  const int tid = threadIdx.x;
#pragma unroll 8
  for (int i = 0; i < 32; ++i) {
    int idx = i * 256 + tid;
    int d2 = idx >> 6, c = idx & 63;
    wT[(c << 7) + (d2 ^ (c & 31))] = w_kv[idx];
  }
#pragma unroll
  for (int i = 0; i < 16; ++i) {
    int idx = i * 256 + tid;
    wq[idx] = w_q[idx] * 0.125f;
    wp[idx] = w_proj[idx];
  }
  const int gr0 = blockIdx.x << 4;
  const int b = gr0 >> 8;
  const int key0 = gr0 & 255;
  {
    const int c = tid & 63;
    const int w = tid >> 6;
#pragma unroll
    for (int pass = 0; pass < 4; ++pass) {
      int row = pass * 4 + w;
      int gr = gr0 + row;
      float y = b_sr[c];
#pragma unroll
      for (int s = 0; s < 4; ++s) y += convP[((s << 11) + gr) * 64 + c];
      float s1 = y, s2 = y * y;
#pragma unroll
      for (int off = 1; off < 64; off <<= 1) {
        s1 += __shfl_xor(s1, off);
        s2 += __shfl_xor(s2, off);
      }
      float mu = s1 * 0.015625f;
      float var = s2 * 0.015625f - mu * mu;
      float rs = rsqrtf(var + 1e-5f);
      rowz[row][c] = (y - mu) * rs * ln_g[c] + ln_b[c];
    }
  }
  __syncthreads();
  {
    const int row = tid >> 4;
    const int c8 = (tid & 15) * 8;
    float acc[8];
#pragma unroll
    for (int j = 0; j < 8; ++j) acc[j] = 0.f;
#pragma unroll
    for (int c = 0; c < 64; ++c) {
      float rz = rowz[row][c];
#pragma unroll
      for (int j = 0; j < 8; ++j) acc[j] += rz * wT[(c << 7) + ((c8 + j) ^ (c & 31))];
    }
    if (c8 < 64) {
#pragma unroll
      for (int j = 0; j < 8; ++j) Kf[row][c8 + j] = acc[j];
    } else {
#pragma unroll
      for (int j = 0; j < 8; ++j) Vf[row][c8 - 64 + j] = acc[j];
    }
  }
  __syncthreads();
  {
    const int row = tid >> 4;
    const int cc4 = (tid & 15) * 4;
    float a[4] = {0.f, 0.f, 0.f, 0.f};
#pragma unroll
    for (int o = 0; o < 64; ++o) {
      float kv = Kf[row][o];
#pragma unroll
      for (int j = 0; j < 4; ++j) a[j] += kv * wq[o * 64 + cc4 + j];
    }
    short* dst = KQ + (size_t)(gr0 + row) * 64 + cc4;
#pragma unroll
    for (int j = 0; j < 4; ++j) dst[j] = f2bf(a[j]);
  }
  {
    const int o = tid >> 2;
    const int k4 = (tid & 3) * 4;
    float v[4] = {0.f, 0.f, 0.f, 0.f};
#pragma unroll
    for (int d = 0; d < 64; ++d) {
      float wv = wp[o * 64 + d];
#pragma unroll
      for (int j = 0; j < 4; ++j) v[j] += wv * Vf[k4 + j][d];
    }
    short* dst = VPT + ((size_t)b << 14) + o * 256 + key0 + k4;
#pragma unroll
    for (int j = 0; j < 4; ++j) dst[j] = f2bf(v[j]);
  }
}

// ---------------- attention v8: v7 + coalesced LDS-transposed epilogue ----
// KQl/VPTl merged into one SMEM array; after the kt loop they are dead and
// reused as per-wave f32 [16][68] transpose scratch -> 256B-segment stores.
__global__ __launch_bounds__(512, 2) void attn_k(
    const float* __restrict__ x, const short* __restrict__ KQ,
    const short* __restrict__ VPT, const float* __restrict__ bproj,
    float* __restrict__ out) {
  __shared__ short SMEM[16384 + 64 * 264];  // KQl (32KB) + VPTl (33KB)
  short* KQl = SMEM;            // rows 128B, 16B-slot ^= (row&7)
  short* VPTl = SMEM + 16384;   // rows padded 528B, 8B-slot ^= (o&7)

  const int tid = threadIdx.x;
  const int lane = tid & 63;
  const int wid = tid >> 6;
  const int b = blockIdx.x >> 6;
  const int n0 = (blockIdx.x & 63) << 8;
  const int g = lane >> 4;
  const int kq = lane & 15;
  const int tok0 = n0 + wid * 32;
  const size_t xbase = ((size_t)b * NTOK + tok0) * 64;

  bf16x8 xa[2][2];
#pragma unroll
  for (int m = 0; m < 2; ++m)
#pragma unroll
    for (int kc = 0; kc < 2; ++kc) {
      const float* p = x + xbase + (size_t)(m * 16 + kq) * 64 + kc * 32 + g * 8;
      xa[m][kc] = cvt8pk(*(const f32x4*)p, *(const f32x4*)(p + 4));
    }
  float bp[4];
#pragma unroll
  for (int nd = 0; nd < 4; ++nd) bp[nd] = bproj[nd * 16 + kq];

  {
    const uint4* Kg = (const uint4*)(KQ + ((size_t)b << 14));
#pragma unroll
    for (int i = 0; i < 4; ++i) {
      int id = i * 512 + tid;
      int row = id >> 3, s = id & 7;
      *(uint4*)(&KQl[(row << 6) + ((s ^ (row & 7)) << 3)]) = Kg[id];
    }
    const uint4* Vg = (const uint4*)(VPT + ((size_t)b << 14));
#pragma unroll
    for (int i = 0; i < 4; ++i) {
      int id = i * 512 + tid;
      int o = id >> 5, s = id & 31;
      uint4 v = Vg[id];
      int p0 = (2 * s) ^ (o & 7);
      int p1 = (2 * s + 1) ^ (o & 7);
      uint2 lo; lo.x = v.x; lo.y = v.y;
      uint2 hi; hi.x = v.z; hi.y = v.w;
      *(uint2*)(&VPTl[o * 264 + p0 * 4]) = lo;
      *(uint2*)(&VPTl[o * 264 + p1 * 4]) = hi;
    }
  }
  __syncthreads();

  f32x4 pv[2][4];
  f32x4 pvs[2];  // rowsum accumulators (ones-MFMA)
#pragma unroll
  for (int m = 0; m < 2; ++m) {
#pragma unroll
    for (int nd = 0; nd < 4; ++nd) pv[m][nd] = (f32x4){0.f, 0.f, 0.f, 0.f};
    pvs[m] = (f32x4){0.f, 0.f, 0.f, 0.f};
  }
  const short one_bf = (short)0x3F80;  // bf16 1.0
  const bf16x8 ones8 = (bf16x8){one_bf, one_bf, one_bf, one_bf,
                                one_bf, one_bf, one_bf, one_bf};

  auto qkchunk = [&](int C, f32x4 (&S)[2][2]) {
#pragma unroll
    for (int kk = 0; kk < 2; ++kk) {
      int key = (2 * C + kk) * 16 + kq;
      bf16x8 kb0 = *(const bf16x8*)(&KQl[(key << 6) + (((0 + g) ^ (key & 7)) << 3)]);
      bf16x8 kb1 = *(const bf16x8*)(&KQl[(key << 6) + (((4 + g) ^ (key & 7)) << 3)]);
#pragma unroll
      for (int m = 0; m < 2; ++m) {
        f32x4 s4 = MFMA(kb0, xa[m][0], ((f32x4){0.f, 0.f, 0.f, 0.f}));
        S[m][kk] = MFMA(kb1, xa[m][1], s4);
      }
    }
  };

  f32x4 scur[2][2], snxt[2][2];
  qkchunk(0, scur);

  __builtin_amdgcn_s_setprio(1);
#pragma unroll
  for (int c = 0; c < 8; ++c) {
    if (c < 7) qkchunk(c + 1, snxt);  // MFMA pipe overlaps the VALU below
    bf16x8 a8[2];
#pragma unroll
    for (int m = 0; m < 2; ++m) {
      f32x4 e0, e1;
#pragma unroll
      for (int r = 0; r < 4; ++r) e0[r] = __expf(scur[m][0][r]);
#pragma unroll
      for (int r = 0; r < 4; ++r) e1[r] = __expf(scur[m][1][r]);
      u32x4 w;
      w[0] = pk2(e0[0], e0[1]);
      w[1] = pk2(e0[2], e0[3]);
      w[2] = pk2(e1[0], e1[1]);
      w[3] = pk2(e1[2], e1[3]);
      a8[m] = __builtin_bit_cast(bf16x8, w);
    }
#pragma unroll
    for (int nd = 0; nd < 4; ++nd) {
      int o = nd * 16 + kq;
      const short* vrow = &VPTl[o * 264];
      int pa = (8 * c + g) ^ (o & 7);
      int pb_ = (8 * c + g + 4) ^ (o & 7);
      bf16x4 lo = *(const bf16x4*)(vrow + pa * 4);
      bf16x4 hi = *(const bf16x4*)(vrow + pb_ * 4);
      bf16x8 vb = (bf16x8){lo[0], lo[1], lo[2], lo[3], hi[0], hi[1], hi[2], hi[3]};
#pragma unroll
      for (int m = 0; m < 2; ++m) pv[m][nd] = MFMA(a8[m], vb, pv[m][nd]);
    }
#pragma unroll
    for (int m = 0; m < 2; ++m) pvs[m] = MFMA(a8[m], ones8, pvs[m]);
#pragma unroll
    for (int m = 0; m < 2; ++m) {
      scur[m][0] = snxt[m][0];
      scur[m][1] = snxt[m][1];
    }
  }
  __builtin_amdgcn_s_setprio(0);

  // ---- epilogue: dead-LDS transpose -> coalesced 256B-segment stores ----
  __syncthreads();  // all waves done with KQl/VPTl
  float* swp = ((float*)SMEM) + wid * (16 * 68);  // 8 waves x 4352B = 34.8KB
#pragma unroll
  for (int m = 0; m < 2; ++m) {
#pragma unroll
    for (int r = 0; r < 4; ++r) {
      float iv = 1.0f / pvs[m][r];
      int row = g * 4 + r;
#pragma unroll
      for (int nd = 0; nd < 4; ++nd)
        swp[row * 68 + nd * 16 + kq] = pv[m][nd][r] * iv + bp[nd];
    }
#pragma unroll
    for (int i = 0; i < 4; ++i) {
      int idx = i * 64 + lane;
      int rl = idx >> 4, seg = idx & 15;
      f32x4 v = *(const f32x4*)(swp + rl * 68 + seg * 4);
      *(f32x4*)(out + xbase + (size_t)(m * 16 + rl) * 64 + seg * 4) = v;
    }
  }
}

extern "C" void kernel_launch(void* const* d_in, const int* in_sizes, int n_in,
                              void* d_out, int out_size, void* d_ws, size_t ws_size,
                              hipStream_t stream) {
  const float* x = (const float*)d_in[0];
  const float* w_q = (const float*)d_in[3];
  const float* w_kv = (const float*)d_in[4];
  const float* w_sr = (const float*)d_in[5];
  const float* b_sr = (const float*)d_in[6];
  const float* ln_g = (const float*)d_in[7];
  const float* ln_b = (const float*)d_in[8];
  const float* w_proj = (const float*)d_in[9];
  const float* b_proj = (const float*)d_in[10];
  float* out = (float*)d_out;

  // workspace 2,621,440 B; KQ/VPT alias W2T (dead after conv_k)
  char* ws = (char*)d_ws;
  short* W2T = (short*)(ws);
  short* KQ = (short*)(ws);
  short* VPT = (short*)(ws + 262144);
  float* convP = (float*)(ws + 524288);

  hipLaunchKernelGGL(prep_k, dim3(64), dim3(256), 0, stream, w_sr, W2T);
  hipLaunchKernelGGL(conv_k, dim3(512), dim3(256), 0, stream, x, W2T, convP);
  hipLaunchKernelGGL(kvkq_k, dim3(128), dim3(256), 0, stream, convP, b_sr, ln_g,
                     ln_b, w_kv, w_q, w_proj, KQ, VPT);
  hipLaunchKernelGGL(attn_k, dim3(512), dim3(512), 0, stream, x, KQ, VPT,
                     b_proj, out);
}

// Round 21
// 45.671 us; speedup vs baseline: 1.0958x; 1.0958x over previous
//
#include <hip/hip_runtime.h>
#include <hip/hip_bf16.h>

#define BATCH 8
#define NTOK 16384

typedef __attribute__((ext_vector_type(8))) short bf16x8;
typedef __attribute__((ext_vector_type(4))) short bf16x4;
typedef __attribute__((ext_vector_type(4))) float f32x4;
typedef __attribute__((ext_vector_type(4))) unsigned int u32x4;

#define MFMA(a, b, c) __builtin_amdgcn_mfma_f32_16x16x32_bf16(a, b, c, 0, 0, 0)

// proven path: RNE f32->bf16 via bit ops
__device__ __forceinline__ short f2bf(float f) {
  unsigned u = __builtin_bit_cast(unsigned, f);
  u = (u + 0x7fffu + ((u >> 16) & 1u)) >> 16;  // RNE
  return (short)u;
}
__device__ __forceinline__ bf16x8 cvt8(f32x4 v0, f32x4 v1) {
  bf16x8 a;
  a[0] = f2bf(v0[0]); a[1] = f2bf(v0[1]); a[2] = f2bf(v0[2]); a[3] = f2bf(v0[3]);
  a[4] = f2bf(v1[0]); a[5] = f2bf(v1[1]); a[6] = f2bf(v1[2]); a[7] = f2bf(v1[3]);
  return a;
}
// HW packed conversion via HIP header (compiler-lowered, NOT hand asm)
__device__ __forceinline__ unsigned pk2(float a, float b) {
  __hip_bfloat162 h = __float22bfloat162_rn(float2{a, b});
  unsigned r;
  __builtin_memcpy(&r, &h, 4);
  return r;
}
__device__ __forceinline__ bf16x8 cvt8pk(f32x4 v0, f32x4 v1) {
  u32x4 w;
  w[0] = pk2(v0[0], v0[1]);
  w[1] = pk2(v0[2], v0[3]);
  w[2] = pk2(v1[1 - 1], v1[1]);
  w[3] = pk2(v1[2], v1[3]);
  return __builtin_bit_cast(bf16x8, w);
}

// ---------------- prep: conv weight transpose via padded LDS tile ---------
__global__ __launch_bounds__(256) void prep_k(const float* __restrict__ w_sr,
                                              short* __restrict__ W2T) {
  __shared__ float tile[64 * 65];
  const int o = blockIdx.x;  // 64 blocks
  const float* src = w_sr + (o << 12);
  short* dst = W2T + (o << 12);
  const int tid = threadIdx.x;
#pragma unroll
  for (int k = 0; k < 16; ++k) {
    int idx = k * 256 + tid;
    int c = idx >> 6, t = idx & 63;
    tile[c * 65 + t] = src[idx];
  }
  __syncthreads();
#pragma unroll
  for (int k = 0; k < 16; ++k) {
    int idx = k * 256 + tid;
    int t = idx >> 6, c = idx & 63;
    dst[idx] = f2bf(tile[c * 65 + t]);
  }
}

// ---------------- conv v2: LDS-staged coalesced x, MFMA GEMM, K-split 4 ---
__global__ __launch_bounds__(256, 4) void conv_k(const float* __restrict__ x,
                                                 const short* __restrict__ W2T,
                                                 float* __restrict__ convP) {
  __shared__ short Axl[2 * 128 * 64];  // 32KB: [ti][col][c]
  const int tid = threadIdx.x;
  const int lane = tid & 63;
  const int nt = tid >> 6;
  const int g = lane >> 4;
  const int kq = lane & 15;          // pj
  const int pblk = blockIdx.x >> 2;  // b*16 + pi
  const int split = blockIdx.x & 3;
  const int pbase = pblk << 4;
  const int b = pbase >> 8;
  const int pi = pblk & 15;
  const size_t xb = (size_t)b * NTOK * 64;
  const int y0 = pi * 8 + split * 2;

#pragma unroll
  for (int i = 0; i < 8; ++i) {
    int cid = i * 256 + tid;
    int row = cid >> 3;               // ti*128 + col
    int ti = row >> 7, col = row & 127;
    int slot = (cid & 7) ^ ((col >> 3) & 7);
    const float* src = x + xb + ((size_t)((y0 + ti) * 128 + col) << 6) + ((cid & 7) << 3);
    bf16x8 v = cvt8(*(const f32x4*)src, *(const f32x4*)(src + 4));
    *(bf16x8*)(&Axl[(row << 6) + (slot << 3)]) = v;
  }
  __syncthreads();

  f32x4 acc = (f32x4){0.f, 0.f, 0.f, 0.f};
  const int c0 = split << 5;
#pragma unroll 4
  for (int c32 = c0; c32 < c0 + 32; ++c32) {
    int t = c32 >> 1;
    int ti = (t >> 3) & 1;
    int tj = t & 7;
    int row = ti * 128 + kq * 8 + tj;
    int slot = (((c32 & 1) << 2) + g) ^ (kq & 7);
    bf16x8 a = *(const bf16x8*)(&Axl[(row << 6) + (slot << 3)]);
    bf16x8 wb = *(const bf16x8*)(W2T + ((nt * 16 + kq) << 12) + (c32 << 5) + (g << 3));
    acc = MFMA(a, wb, acc);
  }
#pragma unroll
  for (int r = 0; r < 4; ++r) {
    int prow = pbase + g * 4 + r;
    convP[((split << 11) + prow) * 64 + nt * 16 + kq] = acc[r];
  }
}

// ---------------- fused: bias + LN + kv-proj + folded projections ---------
// 256 blocks x 8 rows: all 256 CUs active at 2 blocks/CU.
// Per-row math bitwise identical to the proven 16-row version.
__global__ __launch_bounds__(256) void kvkq_k(
    const float* __restrict__ convP, const float* __restrict__ b_sr,
    const float* __restrict__ ln_g, const float* __restrict__ ln_b,
    const float* __restrict__ w_kv, const float* __restrict__ w_q,
    const float* __restrict__ w_proj, short* __restrict__ KQ,
    short* __restrict__ VPT) {
  __shared__ float wT[64 * 128];   // w_kv [c][d ^ (c&31)]
  __shared__ float wq[64 * 64];    // SCALE*w_q [o][cc]
  __shared__ float wp[64 * 64];    // w_proj [o][d]
  __shared__ float rowz[8][64];
  __shared__ float Kf[8][68];
  __shared__ float Vf[8][68];
  const int tid = threadIdx.x;
#pragma unroll 8
  for (int i = 0; i < 32; ++i) {
    int idx = i * 256 + tid;
    int d2 = idx >> 6, c = idx & 63;
    wT[(c << 7) + (d2 ^ (c & 31))] = w_kv[idx];
  }
#pragma unroll
  for (int i = 0; i < 16; ++i) {
    int idx = i * 256 + tid;
    wq[idx] = w_q[idx] * 0.125f;
    wp[idx] = w_proj[idx];
  }
  const int gr0 = blockIdx.x << 3;   // 8 rows per block
  const int b = gr0 >> 8;
  const int key0 = gr0 & 255;
  {
    const int c = tid & 63;
    const int w = tid >> 6;  // 4 waves; 2 passes x 4 rows
#pragma unroll
    for (int pass = 0; pass < 2; ++pass) {
      int row = pass * 4 + w;
      int gr = gr0 + row;
      float y = b_sr[c];
#pragma unroll
      for (int s = 0; s < 4; ++s) y += convP[((s << 11) + gr) * 64 + c];
      float s1 = y, s2 = y * y;
#pragma unroll
      for (int off = 1; off < 64; off <<= 1) {
        s1 += __shfl_xor(s1, off);
        s2 += __shfl_xor(s2, off);
      }
      float mu = s1 * 0.015625f;
      float var = s2 * 0.015625f - mu * mu;
      float rs = rsqrtf(var + 1e-5f);
      rowz[row][c] = (y - mu) * rs * ln_g[c] + ln_b[c];
    }
  }
  __syncthreads();
  // K,V: row = tid>>5 (8 rows x 32 threads), 4 channels each of 128
  {
    const int row = tid >> 5;
    const int c4 = (tid & 31) * 4;  // 0..124
    float acc[4] = {0.f, 0.f, 0.f, 0.f};
#pragma unroll
    for (int c = 0; c < 64; ++c) {
      float rz = rowz[row][c];
#pragma unroll
      for (int j = 0; j < 4; ++j) acc[j] += rz * wT[(c << 7) + ((c4 + j) ^ (c & 31))];
    }
    if (c4 < 64) {
#pragma unroll
      for (int j = 0; j < 4; ++j) Kf[row][c4 + j] = acc[j];
    } else {
#pragma unroll
      for (int j = 0; j < 4; ++j) Vf[row][c4 - 64 + j] = acc[j];
    }
  }
  __syncthreads();
  // KQ: row = tid>>5 (8 rows), 2 cols each
  {
    const int row = tid >> 5;
    const int cc2 = (tid & 31) * 2;
    float a[2] = {0.f, 0.f};
#pragma unroll
    for (int o = 0; o < 64; ++o) {
      float kv = Kf[row][o];
#pragma unroll
      for (int j = 0; j < 2; ++j) a[j] += kv * wq[o * 64 + cc2 + j];
    }
    short* dst = KQ + (size_t)(gr0 + row) * 64 + cc2;
#pragma unroll
    for (int j = 0; j < 2; ++j) dst[j] = f2bf(a[j]);
  }
  // VPT: o = tid>>2 (64 o's), 2 keys each
  {
    const int o = tid >> 2;
    const int k2 = (tid & 3) * 2;
    float v[2] = {0.f, 0.f};
#pragma unroll
    for (int d = 0; d < 64; ++d) {
      float wv = wp[o * 64 + d];
#pragma unroll
      for (int j = 0; j < 2; ++j) v[j] += wv * Vf[k2 + j][d];
    }
    short* dst = VPT + ((size_t)b << 14) + o * 256 + key0 + k2;
#pragma unroll
    for (int j = 0; j < 2; ++j) dst[j] = f2bf(v[j]);
  }
}

// ---------------- attention v7 (R17-proven): 2-stage + rowsum-via-MFMA ----
__global__ __launch_bounds__(512, 2) void attn_k(
    const float* __restrict__ x, const short* __restrict__ KQ,
    const short* __restrict__ VPT, const float* __restrict__ bproj,
    float* __restrict__ out) {
  __shared__ short KQl[256 * 64];   // rows 128B, 16B-slot ^= (row&7)
  __shared__ short VPTl[64 * 264];  // rows padded 528B, 8B-slot ^= (o&7)

  const int tid = threadIdx.x;
  const int lane = tid & 63;
  const int wid = tid >> 6;
  const int b = blockIdx.x >> 6;
  const int n0 = (blockIdx.x & 63) << 8;
  const int g = lane >> 4;
  const int kq = lane & 15;
  const int tok0 = n0 + wid * 32;
  const size_t xbase = ((size_t)b * NTOK + tok0) * 64;

  bf16x8 xa[2][2];
#pragma unroll
  for (int m = 0; m < 2; ++m)
#pragma unroll
    for (int kc = 0; kc < 2; ++kc) {
      const float* p = x + xbase + (size_t)(m * 16 + kq) * 64 + kc * 32 + g * 8;
      xa[m][kc] = cvt8pk(*(const f32x4*)p, *(const f32x4*)(p + 4));
    }
  float bp[4];
#pragma unroll
  for (int nd = 0; nd < 4; ++nd) bp[nd] = bproj[nd * 16 + kq];

  {
    const uint4* Kg = (const uint4*)(KQ + ((size_t)b << 14));
#pragma unroll
    for (int i = 0; i < 4; ++i) {
      int id = i * 512 + tid;
      int row = id >> 3, s = id & 7;
      *(uint4*)(&KQl[(row << 6) + ((s ^ (row & 7)) << 3)]) = Kg[id];
    }
    const uint4* Vg = (const uint4*)(VPT + ((size_t)b << 14));
#pragma unroll
    for (int i = 0; i < 4; ++i) {
      int id = i * 512 + tid;
      int o = id >> 5, s = id & 31;
      uint4 v = Vg[id];
      int p0 = (2 * s) ^ (o & 7);
      int p1 = (2 * s + 1) ^ (o & 7);
      uint2 lo; lo.x = v.x; lo.y = v.y;
      uint2 hi; hi.x = v.z; hi.y = v.w;
      *(uint2*)(&VPTl[o * 264 + p0 * 4]) = lo;
      *(uint2*)(&VPTl[o * 264 + p1 * 4]) = hi;
    }
  }
  __syncthreads();

  f32x4 pv[2][4];
  f32x4 pvs[2];  // rowsum accumulators (ones-MFMA)
#pragma unroll
  for (int m = 0; m < 2; ++m) {
#pragma unroll
    for (int nd = 0; nd < 4; ++nd) pv[m][nd] = (f32x4){0.f, 0.f, 0.f, 0.f};
    pvs[m] = (f32x4){0.f, 0.f, 0.f, 0.f};
  }
  const short one_bf = (short)0x3F80;  // bf16 1.0
  const bf16x8 ones8 = (bf16x8){one_bf, one_bf, one_bf, one_bf,
                                one_bf, one_bf, one_bf, one_bf};

  auto qkchunk = [&](int C, f32x4 (&S)[2][2]) {
#pragma unroll
    for (int kk = 0; kk < 2; ++kk) {
      int key = (2 * C + kk) * 16 + kq;
      bf16x8 kb0 = *(const bf16x8*)(&KQl[(key << 6) + (((0 + g) ^ (key & 7)) << 3)]);
      bf16x8 kb1 = *(const bf16x8*)(&KQl[(key << 6) + (((4 + g) ^ (key & 7)) << 3)]);
#pragma unroll
      for (int m = 0; m < 2; ++m) {
        f32x4 s4 = MFMA(kb0, xa[m][0], ((f32x4){0.f, 0.f, 0.f, 0.f}));
        S[m][kk] = MFMA(kb1, xa[m][1], s4);
      }
    }
  };

  f32x4 scur[2][2], snxt[2][2];
  qkchunk(0, scur);

  __builtin_amdgcn_s_setprio(1);
#pragma unroll
  for (int c = 0; c < 8; ++c) {
    if (c < 7) qkchunk(c + 1, snxt);  // MFMA pipe overlaps the VALU below
    bf16x8 a8[2];
#pragma unroll
    for (int m = 0; m < 2; ++m) {
      f32x4 e0, e1;
#pragma unroll
      for (int r = 0; r < 4; ++r) e0[r] = __expf(scur[m][0][r]);
#pragma unroll
      for (int r = 0; r < 4; ++r) e1[r] = __expf(scur[m][1][r]);
      u32x4 w;
      w[0] = pk2(e0[0], e0[1]);
      w[1] = pk2(e0[2], e0[3]);
      w[2] = pk2(e1[0], e1[1]);
      w[3] = pk2(e1[2], e1[3]);
      a8[m] = __builtin_bit_cast(bf16x8, w);
    }
#pragma unroll
    for (int nd = 0; nd < 4; ++nd) {
      int o = nd * 16 + kq;
      const short* vrow = &VPTl[o * 264];
      int pa = (8 * c + g) ^ (o & 7);
      int pb_ = (8 * c + g + 4) ^ (o & 7);
      bf16x4 lo = *(const bf16x4*)(vrow + pa * 4);
      bf16x4 hi = *(const bf16x4*)(vrow + pb_ * 4);
      bf16x8 vb = (bf16x8){lo[0], lo[1], lo[2], lo[3], hi[0], hi[1], hi[2], hi[3]};
#pragma unroll
      for (int m = 0; m < 2; ++m) pv[m][nd] = MFMA(a8[m], vb, pv[m][nd]);
    }
#pragma unroll
    for (int m = 0; m < 2; ++m) pvs[m] = MFMA(a8[m], ones8, pvs[m]);
#pragma unroll
    for (int m = 0; m < 2; ++m) {
      scur[m][0] = snxt[m][0];
      scur[m][1] = snxt[m][1];
    }
  }
  __builtin_amdgcn_s_setprio(0);

  // normalize + store: rinv is lane-local (pvs shares pv's C-layout)
#pragma unroll
  for (int m = 0; m < 2; ++m)
#pragma unroll
    for (int r = 0; r < 4; ++r) {
      float iv = 1.0f / pvs[m][r];
      size_t rowoff = xbase + (size_t)(m * 16 + g * 4 + r) * 64;
#pragma unroll
      for (int nd = 0; nd < 4; ++nd)
        out[rowoff + nd * 16 + kq] = pv[m][nd][r] * iv + bp[nd];
    }
}

extern "C" void kernel_launch(void* const* d_in, const int* in_sizes, int n_in,
                              void* d_out, int out_size, void* d_ws, size_t ws_size,
                              hipStream_t stream) {
  const float* x = (const float*)d_in[0];
  const float* w_q = (const float*)d_in[3];
  const float* w_kv = (const float*)d_in[4];
  const float* w_sr = (const float*)d_in[5];
  const float* b_sr = (const float*)d_in[6];
  const float* ln_g = (const float*)d_in[7];
  const float* ln_b = (const float*)d_in[8];
  const float* w_proj = (const float*)d_in[9];
  const float* b_proj = (const float*)d_in[10];
  float* out = (float*)d_out;

  // workspace 2,621,440 B; KQ/VPT alias W2T (dead after conv_k)
  char* ws = (char*)d_ws;
  short* W2T = (short*)(ws);
  short* KQ = (short*)(ws);
  short* VPT = (short*)(ws + 262144);
  float* convP = (float*)(ws + 524288);

  hipLaunchKernelGGL(prep_k, dim3(64), dim3(256), 0, stream, w_sr, W2T);
  hipLaunchKernelGGL(conv_k, dim3(512), dim3(256), 0, stream, x, W2T, convP);
  hipLaunchKernelGGL(kvkq_k, dim3(256), dim3(256), 0, stream, convP, b_sr, ln_g,
                     ln_b, w_kv, w_q, w_proj, KQ, VPT);
  hipLaunchKernelGGL(attn_k, dim3(512), dim3(512), 0, stream, x, KQ, VPT,
                     b_proj, out);
}